// Round 6
// baseline (452.645 us; speedup 1.0000x reference)
//
#include <hip/hip_runtime.h>

typedef unsigned short ushort_t;
typedef unsigned int uint32;
typedef __attribute__((ext_vector_type(8))) short short8;
typedef __attribute__((ext_vector_type(4))) float f32x4;

#define T_STEPS 256
#define LOG2E   1.4426950408889634f
#define LOG2E2  2.8853900817779268f

static __device__ __forceinline__ ushort_t f2bf(float f) {
    uint32 u = __float_as_uint(f);
    u += 0x7FFFu + ((u >> 16) & 1u);
    return (ushort_t)(u >> 16);
}
static __device__ __forceinline__ float rcp_(float x) { return __builtin_amdgcn_rcpf(x); }
static __device__ __forceinline__ float ex2_(float x) { return __builtin_amdgcn_exp2f(x); }
// sigmoid with pre-scaled arg: x already multiplied by log2e
static __device__ __forceinline__ float sigp_(float x) { return rcp_(1.0f + ex2_(-x)); }

// ---------------- prep: pack W into MFMA A-fragments (8-wave / 4-tile geometry) ----
// Wave w in [0,8), tile tq in [0,4). Tile row m = kgA*4 + j  (j = gate i,f,g,o)
// -> weight row = j*128 + hc, hc = w*16 + kgA*4 + tq
// (thread (w,kgA,n)'s 4 outputs across tq are CONTIGUOUS h-cols w*16+kgA*4+0..3).
// A-frag (16x16x32): lane holds A[m = lane&15][k = (lane>>4)*8 + e].
// Rows pre-scaled: log2e for i,f,o ; 2*log2e for g (j==2).
template<int LAYER>
__global__ void prep_frag(const float* __restrict__ Whh, const float* __restrict__ Wih,
                          ushort_t* __restrict__ wfrag) {
    constexpr int KT  = (LAYER == 0) ? 6 : 8;
    constexpr int DIN = (LAYER == 0) ? 64 : 128;
    int i = blockIdx.x * 256 + threadIdx.x;
    int e    = i & 7;
    int lane = (i >> 3) & 63;
    int r3   = i >> 9;
    int kt   = r3 % KT;
    int r4   = r3 / KT;
    int tq   = r4 & 3;
    int w    = r4 >> 2;
    if (w >= 8) return;
    int ml  = lane & 15;
    int kgA = ml >> 2;
    int j   = ml & 3;
    int k   = kt * 32 + (lane >> 4) * 8 + e;
    int row = j * 128 + w * 16 + kgA * 4 + tq;
    float scale = (j == 2) ? LOG2E2 : LOG2E;
    float v = (k < 128) ? Whh[row * 128 + k] : Wih[row * DIN + (k - 128)];
    wfrag[i] = f2bf(v * scale);
}

__global__ void prep_bias(const float* __restrict__ bih0, const float* __restrict__ bhh0,
                          const float* __restrict__ bih1, const float* __restrict__ bhh1,
                          float* __restrict__ bp0, float* __restrict__ bp1) {
    int i = blockIdx.x * 256 + threadIdx.x;   // 0..1023
    int p = i & 511;
    int w = p >> 6, tq = (p >> 4) & 3, kgA = (p >> 2) & 3, j = p & 3;
    int row = j * 128 + w * 16 + kgA * 4 + tq;
    float scale = (j == 2) ? LOG2E2 : LOG2E;
    if (i < 512) bp0[p] = (bih0[row] + bhh0[row]) * scale;
    else         bp1[p] = (bih1[row] + bhh1[row]) * scale;
}

// ---------------- persistent LSTM layer kernel (8 waves x 4 tiles) ----------------
// 64 blocks x 512 threads (8 waves, 2/SIMD -> 256-VGPR budget). Block owns 16 batch.
// Wave w owns gate rows [w*64, w*64+64) = 4 tiles; thread outputs 4 contiguous h-cols.
// LDS k-major frag layout: feature f of batch n at ushort [f>>5][(f>>3)&3][n][f&7]
//   -> B-frag ds_read_b128 lane-contiguous (conflict-free), shared across 4 tiles
//   -> h-write one ds_write_b64 (4 bf16).
// Layer0 stores per-step k-major 4KB records (u32 idx == LDS u32 idx); layer1 stages
// them back with a straight coalesced copy.
template<int LAYER>
__global__ __launch_bounds__(512)
void lstm_layer(const float* __restrict__ xin_f32,      // LAYER 0: [B,T,64] f32
                const uint32* __restrict__ xin_rec,     // LAYER 1: k-major records
                const ushort_t* __restrict__ wfrag,
                const float* __restrict__ biasp,
                uint32* __restrict__ hout,              // LAYER 0 out: k-major records
                float* __restrict__ lastH) {            // LAYER 1 out: [B,128] f32
    constexpr int KT = (LAYER == 0) ? 6 : 8;
    constexpr int KX = KT - 4;
    __shared__ ushort_t hb[2 * 2048];                   // 8 KiB
    __shared__ ushort_t xb[2 * KX * 512];               // 4 or 8 KiB

    const int tid  = threadIdx.x;
    const int w    = tid >> 6;
    const int lane = tid & 63;
    const int n    = lane & 15;
    const int kg   = lane >> 4;
    const int b0   = blockIdx.x * 16;

    // weights -> registers (held entire kernel): 4 tiles x KT frags
    short8 wf[4][KT];
#pragma unroll
    for (int tq = 0; tq < 4; ++tq)
#pragma unroll
        for (int kt = 0; kt < KT; ++kt)
            wf[tq][kt] = *(const short8*)&wfrag[(((w * 4 + tq) * KT + kt) * 64 + lane) * 8];

    f32x4 bias[4];
#pragma unroll
    for (int tq = 0; tq < 4; ++tq)
        bias[tq] = *(const f32x4*)&biasp[w * 64 + tq * 16 + kg * 4];

    float cc[4] = {0.f, 0.f, 0.f, 0.f};
    const int f0   = w * 16 + kg * 4;                   // first of 4 contiguous h-cols
    const int idxA = ((f0 >> 5) * 4 + ((f0 >> 3) & 3)) * 64 + n * 4 + ((f0 & 7) >> 1);

    // L0 x staging map: thread loads float2 (features skk, skk+1) of batch sn
    const int se  = (tid & 3) * 2;
    const int sn  = (tid >> 2) & 15;
    const int skg = (tid >> 6) & 3;
    const int skx = tid >> 8;                           // 0..1
    const int skk = skx * 32 + skg * 8 + se;
    const long xbase    = (long)(b0 + sn) * (T_STEPS * 64) + skk;
    const int  sidx     = (skx * 4 + skg) * 64 + sn * 4 + (se >> 1);  // u32 idx in xb half
    const long rec_base = (long)blockIdx.x * (T_STEPS * 1024);        // u32 units

    // zero h state (buf 0 = 1024 u32)
    ((uint32*)hb)[tid] = 0u;
    ((uint32*)hb)[tid + 512] = 0u;
    // prefill x for t=0
    if (LAYER == 0) {
        float2 xv = *(const float2*)&xin_f32[xbase];
        uint32 xp; asm("v_cvt_pk_bf16_f32 %0, %1, %2" : "=v"(xp) : "v"(xv.x), "v"(xv.y));
        ((uint32*)xb)[sidx] = xp;
    } else {
        ((uint32*)xb)[tid] = xin_rec[rec_base + tid];
        ((uint32*)xb)[tid + 512] = xin_rec[rec_base + tid + 512];
    }
    __syncthreads();

#define STEP(CUR, NXT, T)                                                          \
    {                                                                              \
        const bool pf = ((T) + 1 < T_STEPS);                                       \
        float2 xf = {0.f, 0.f}; uint32 xu0 = 0, xu1 = 0;                           \
        if (pf) {                                                                  \
            if (LAYER == 0) {                                                      \
                xf = *(const float2*)&xin_f32[xbase + ((T) + 1) * 64];             \
            } else {                                                               \
                xu0 = xin_rec[rec_base + ((T) + 1) * 1024 + tid];                  \
                xu1 = xin_rec[rec_base + ((T) + 1) * 1024 + tid + 512];            \
            }                                                                      \
        }                                                                          \
        short8 hfr[4];                                                             \
        _Pragma("unroll")                                                          \
        for (int kt = 0; kt < 4; ++kt)                                             \
            hfr[kt] = *(const short8*)&hb[(CUR) * 2048 + kt * 512 + kg * 128 + n * 8]; \
        short8 xfr[KX];                                                            \
        _Pragma("unroll")                                                          \
        for (int kx = 0; kx < KX; ++kx)                                            \
            xfr[kx] = *(const short8*)&xb[(CUR) * (KX * 512) + kx * 512 + kg * 128 + n * 8]; \
        f32x4 acc[4];                                                              \
        _Pragma("unroll")                                                          \
        for (int tq = 0; tq < 4; ++tq) {                                           \
            acc[tq] = __builtin_amdgcn_mfma_f32_16x16x32_bf16(wf[tq][0], hfr[0], bias[tq], 0, 0, 0); \
            _Pragma("unroll")                                                      \
            for (int kt = 1; kt < 4; ++kt)                                         \
                acc[tq] = __builtin_amdgcn_mfma_f32_16x16x32_bf16(wf[tq][kt], hfr[kt], acc[tq], 0, 0, 0); \
            _Pragma("unroll")                                                      \
            for (int kx = 0; kx < KX; ++kx)                                        \
                acc[tq] = __builtin_amdgcn_mfma_f32_16x16x32_bf16(wf[tq][4 + kx], xfr[kx], acc[tq], 0, 0, 0); \
        }                                                                          \
        float hv0, hv1, hv2, hv3;                                                  \
        {                                                                          \
            float i_, f_, g_, o_;                                                  \
            i_ = sigp_(acc[0][0]); f_ = sigp_(acc[0][1]);                          \
            g_ = fmaf(2.f, sigp_(acc[0][2]), -1.f); o_ = sigp_(acc[0][3]);         \
            cc[0] = fmaf(f_, cc[0], i_ * g_);                                      \
            hv0 = o_ * fmaf(2.f, sigp_(cc[0] * LOG2E2), -1.f);                     \
            i_ = sigp_(acc[1][0]); f_ = sigp_(acc[1][1]);                          \
            g_ = fmaf(2.f, sigp_(acc[1][2]), -1.f); o_ = sigp_(acc[1][3]);         \
            cc[1] = fmaf(f_, cc[1], i_ * g_);                                      \
            hv1 = o_ * fmaf(2.f, sigp_(cc[1] * LOG2E2), -1.f);                     \
            i_ = sigp_(acc[2][0]); f_ = sigp_(acc[2][1]);                          \
            g_ = fmaf(2.f, sigp_(acc[2][2]), -1.f); o_ = sigp_(acc[2][3]);         \
            cc[2] = fmaf(f_, cc[2], i_ * g_);                                      \
            hv2 = o_ * fmaf(2.f, sigp_(cc[2] * LOG2E2), -1.f);                     \
            i_ = sigp_(acc[3][0]); f_ = sigp_(acc[3][1]);                          \
            g_ = fmaf(2.f, sigp_(acc[3][2]), -1.f); o_ = sigp_(acc[3][3]);         \
            cc[3] = fmaf(f_, cc[3], i_ * g_);                                      \
            hv3 = o_ * fmaf(2.f, sigp_(cc[3] * LOG2E2), -1.f);                     \
        }                                                                          \
        uint32 hp0, hp1;                                                           \
        asm("v_cvt_pk_bf16_f32 %0, %1, %2" : "=v"(hp0) : "v"(hv0), "v"(hv1));      \
        asm("v_cvt_pk_bf16_f32 %0, %1, %2" : "=v"(hp1) : "v"(hv2), "v"(hv3));      \
        uint2 hpv; hpv.x = hp0; hpv.y = hp1;                                       \
        *(uint2*)&((uint32*)hb)[(NXT) * 1024 + idxA] = hpv;                        \
        if (LAYER == 1 && (T) == T_STEPS - 1) {                                    \
            f32x4 hv4 = {hv0, hv1, hv2, hv3};                                      \
            *(f32x4*)&lastH[(long)(b0 + n) * 128 + f0] = hv4;                      \
        }                                                                          \
        if (pf) {                                                                  \
            if (LAYER == 0) {                                                      \
                uint32 xp; asm("v_cvt_pk_bf16_f32 %0, %1, %2" : "=v"(xp) : "v"(xf.x), "v"(xf.y)); \
                ((uint32*)xb)[(NXT) * (KX * 256) + sidx] = xp;                     \
            } else {                                                               \
                ((uint32*)xb)[(NXT) * (KX * 256) + tid] = xu0;                     \
                ((uint32*)xb)[(NXT) * (KX * 256) + tid + 512] = xu1;               \
            }                                                                      \
        }                                                                          \
        if (LAYER == 0)                                                            \
            *(uint2*)&hout[rec_base + (long)(T) * 1024 + idxA] = hpv;              \
        __syncthreads();                                                           \
    }

#pragma unroll 1
    for (int t = 0; t < T_STEPS; t += 2) {
        STEP(0, 1, t)
        STEP(1, 0, t + 1)
    }
#undef STEP
}

// ---------------- head: LayerNorm + fc1(relu) + fc2 ----------------
__global__ __launch_bounds__(256)
void head_kernel(const float* __restrict__ lastH,
                 const float* __restrict__ ln_g, const float* __restrict__ ln_b,
                 const float* __restrict__ fc1w, const float* __restrict__ fc1b,
                 const float* __restrict__ fc2w, const float* __restrict__ fc2b,
                 float* __restrict__ out) {
    __shared__ float ylds[4][128];
    int w = threadIdx.x >> 6, lane = threadIdx.x & 63;
    int row = blockIdx.x * 4 + w;
    float x0 = lastH[row * 128 + lane];
    float x1 = lastH[row * 128 + 64 + lane];
    float s = x0 + x1;
    for (int off = 32; off; off >>= 1) s += __shfl_xor(s, off);
    float mu = s * (1.f / 128.f);
    float d0 = x0 - mu, d1 = x1 - mu;
    float v = d0 * d0 + d1 * d1;
    for (int off = 32; off; off >>= 1) v += __shfl_xor(v, off);
    float rs = rsqrtf(v * (1.f / 128.f) + 1e-5f);
    ylds[w][lane]      = d0 * rs * ln_g[lane]      + ln_b[lane];
    ylds[w][lane + 64] = d1 * rs * ln_g[lane + 64] + ln_b[lane + 64];
    __syncthreads();
    float a = fc1b[lane];
#pragma unroll 4
    for (int k = 0; k < 128; ++k) a += ylds[w][k] * fc1w[lane * 128 + k];
    float r = fmaxf(a, 0.f) * fc2w[lane];
    for (int off = 32; off; off >>= 1) r += __shfl_xor(r, off);
    if (lane == 0) out[row] = r + fc2b[0];
}

extern "C" void kernel_launch(void* const* d_in, const int* in_sizes, int n_in,
                              void* d_out, int out_size, void* d_ws, size_t ws_size,
                              hipStream_t stream) {
    const float* x    = (const float*)d_in[0];
    const float* Wih0 = (const float*)d_in[1];
    const float* Whh0 = (const float*)d_in[2];
    const float* bih0 = (const float*)d_in[3];
    const float* bhh0 = (const float*)d_in[4];
    const float* Wih1 = (const float*)d_in[5];
    const float* Whh1 = (const float*)d_in[6];
    const float* bih1 = (const float*)d_in[7];
    const float* bhh1 = (const float*)d_in[8];
    const float* ln_g = (const float*)d_in[9];
    const float* ln_b = (const float*)d_in[10];
    const float* fc1w = (const float*)d_in[11];
    const float* fc1b = (const float*)d_in[12];
    const float* fc2w = (const float*)d_in[13];
    const float* fc2b = (const float*)d_in[14];

    char* ws = (char*)d_ws;
    uint32*   h1k   = (uint32*)  (ws);                 // 64 blk x 256 t x 4 KiB = 64 MiB
    ushort_t* wf0   = (ushort_t*)(ws + 67108864);      // 192 KiB
    ushort_t* wf1   = (ushort_t*)(ws + 67305472);      // 256 KiB
    float*    bp0   = (float*)   (ws + 67567616);      // 2 KiB
    float*    bp1   = (float*)   (ws + 67569664);      // 2 KiB
    float*    lastH = (float*)   (ws + 67571712);      // 512 KiB

    prep_frag<0><<<384, 256, 0, stream>>>(Whh0, Wih0, wf0);
    prep_frag<1><<<512, 256, 0, stream>>>(Whh1, Wih1, wf1);
    prep_bias<<<4, 256, 0, stream>>>(bih0, bhh0, bih1, bhh1, bp0, bp1);

    lstm_layer<0><<<64, 512, 0, stream>>>(x, nullptr, wf0, bp0, h1k, nullptr);
    lstm_layer<1><<<64, 512, 0, stream>>>(nullptr, h1k, wf1, bp1, nullptr, lastH);

    head_kernel<<<256, 256, 0, stream>>>(lastH, ln_g, ln_b, fc1w, fc1b, fc2w, fc2b,
                                         (float*)d_out);
}